// Round 1
// baseline (16001.819 us; speedup 1.0000x reference)
//
#include <hip/hip_runtime.h>
#include <math.h>

#define CCH 256
#define HWP 65536

// ---- ws layout (bytes) ----
static const size_t BUF_B_OFF = 67108864;        // bufA @0 (64MB), bufB @64MB
static const size_t TAIL_OFF  = 134217728;
static const size_t KEYS_OFF  = TAIL_OFF;                // 65536*4
static const size_t HIST_OFF  = TAIL_OFF + 262144;       // 256*4
static const size_t STATE_OFF = TAIL_OFF + 263168;       // small struct
static const size_t IDX_OFF   = TAIL_OFF + 263424;       // 2048*4
static const size_t EQ_OFF    = TAIL_OFF + 271616;       // 4096*4
// overlaid into bufB region (bufB dead after stage-5 conv):
static const size_t Q_OFF   = BUF_B_OFF + 0;
static const size_t K_OFF   = BUF_B_OFF + 2097152;
static const size_t V_OFF   = BUF_B_OFF + 4194304;
static const size_t OA_OFF  = BUF_B_OFF + 6291456;
static const size_t WTI_OFF = BUF_B_OFF + 8388608;       // in_w^T 768*256*4
static const size_t WTO_OFF = BUF_B_OFF + 9437184;       // out_w^T 256*256*4

struct SelState { unsigned int P; int kneed; int nGreater; int nEqual; };

__global__ void k_init(unsigned int* hist, SelState* st) {
  int t = threadIdx.x;
  hist[t] = 0;
  if (t == 0) { st->P = 0u; st->kneed = 2048; st->nGreater = 0; st->nEqual = 0; }
}

// 1x1 conv 768->256 on 8x8
__global__ void k_wtconv(const float* __restrict__ swint, const float* __restrict__ w,
                         const float* __restrict__ b, float* __restrict__ out) {
  int co = blockIdx.x, p = threadIdx.x;
  float acc = b[co];
  for (int ci = 0; ci < 768; ++ci) acc += swint[ci * 64 + p] * w[co * 768 + ci];
  out[co * 64 + p] = acc;
}

// deconv 4x4 stride2 pad2 + bias + relu. input S x S x 256 -> output 2S x 2S x 256
template <int S>
__global__ __launch_bounds__(256) void k_deconv(const float* __restrict__ x,
                                                const float* __restrict__ w,
                                                const float* __restrict__ bias,
                                                float* __restrict__ y) {
  const int SO = 2 * S;
  const int TX = SO / 16;
  int co = blockIdx.y;
  int tile = blockIdx.x;
  int ty0 = (tile / TX) * 16, tx0 = (tile % TX) * 16;
  int t = threadIdx.x;
  int ly = t >> 4, lx = t & 15;
  int oy = ty0 + ly, ox = tx0 + lx;
  int iyb = (ty0 >> 1) - 1, ixb = (tx0 >> 1) - 1;
  int p = oy & 1, q = ox & 1;
  int iyA = ((oy + p - 2) >> 1) - iyb;   // local row of first tap (exact: even >> 1)
  int ixA = ((ox + q - 2) >> 1) - ixb;
  int i00 = (3 - p) * 4 + (3 - q);
  int i01 = (3 - p) * 4 + (1 - q);
  int i10 = (1 - p) * 4 + (3 - q);
  int i11 = (1 - p) * 4 + (1 - q);
  __shared__ float lx_s[8][10][10];
  __shared__ float lw_s[8][16];
  float acc = bias[co];
  for (int c0 = 0; c0 < CCH; c0 += 8) {
    __syncthreads();
    for (int i = t; i < 800; i += 256) {
      int u = i / 100, rem = i % 100;
      int r = rem / 10, c = rem % 10;
      int gy = iyb + r, gx = ixb + c;
      float v = 0.f;
      if (gy >= 0 && gy < S && gx >= 0 && gx < S)
        v = x[(size_t)(c0 + u) * S * S + gy * S + gx];
      lx_s[u][r][c] = v;
    }
    if (t < 128) {
      int u = t >> 4, e = t & 15;
      lw_s[u][e] = w[(size_t)(c0 + u) * 4096 + co * 16 + e];
    }
    __syncthreads();
#pragma unroll
    for (int u = 0; u < 8; ++u) {
      acc += lx_s[u][iyA][ixA]     * lw_s[u][i00]
           + lx_s[u][iyA][ixA + 1] * lw_s[u][i01]
           + lx_s[u][iyA + 1][ixA]     * lw_s[u][i10]
           + lx_s[u][iyA + 1][ixA + 1] * lw_s[u][i11];
    }
  }
  acc = fmaxf(acc, 0.f);
  y[(size_t)co * SO * SO + oy * SO + ox] = acc;
}

// conv 3x3 pad1 + bias (no relu). S x S x 256 -> S x S x 256
template <int S>
__global__ __launch_bounds__(256) void k_conv3(const float* __restrict__ x,
                                               const float* __restrict__ w,
                                               const float* __restrict__ bias,
                                               float* __restrict__ y) {
  const int TX = S / 16;
  int co = blockIdx.y;
  int tile = blockIdx.x;
  int ty0 = (tile / TX) * 16, tx0 = (tile % TX) * 16;
  int t = threadIdx.x;
  int ly = t >> 4, lx = t & 15;
  __shared__ float lds[8][18][18];
  float acc = bias[co];
  for (int c0 = 0; c0 < CCH; c0 += 8) {
    __syncthreads();
    for (int i = t; i < 8 * 324; i += 256) {
      int u = i / 324, rem = i % 324;
      int r = rem / 18, c = rem % 18;
      int gy = ty0 - 1 + r, gx = tx0 - 1 + c;
      float v = 0.f;
      if (gy >= 0 && gy < S && gx >= 0 && gx < S)
        v = x[(size_t)(c0 + u) * S * S + gy * S + gx];
      lds[u][r][c] = v;
    }
    __syncthreads();
#pragma unroll
    for (int u = 0; u < 8; ++u) {
      const float* wp = w + ((size_t)co * CCH + (c0 + u)) * 9;
#pragma unroll
      for (int dy = 0; dy < 3; ++dy)
#pragma unroll
        for (int dx = 0; dx < 3; ++dx)
          acc += lds[u][ly + dy][lx + dx] * wp[dy * 3 + dx];
    }
  }
  y[(size_t)co * S * S + (size_t)(ty0 + ly) * S + (tx0 + lx)] = acc;
}

// gate logit (sigmoid/bias monotonic -> rank raw dot), to orderable uint key
__global__ void k_gate(const float* __restrict__ down, const float* __restrict__ gw,
                       unsigned int* __restrict__ keys) {
  int p = blockIdx.x * 256 + threadIdx.x;
  float acc = 0.f;
  for (int c = 0; c < CCH; ++c) acc += down[(size_t)c * HWP + p] * gw[c];
  unsigned int u = __float_as_uint(acc);
  keys[p] = (u & 0x80000000u) ? ~u : (u | 0x80000000u);
}

__global__ void k_hist(const unsigned int* __restrict__ keys, unsigned int* hist,
                       const SelState* st, int r) {
  __shared__ unsigned int lh[256];
  int t = threadIdx.x;
  lh[t] = 0;
  __syncthreads();
  unsigned int key = keys[blockIdx.x * 256 + t];
  bool ok = (r == 0) || ((key >> (32 - 8 * r)) == st->P);
  if (ok) atomicAdd(&lh[(key >> (24 - 8 * r)) & 255u], 1u);
  __syncthreads();
  if (lh[t]) atomicAdd(&hist[t], lh[t]);
}

__global__ void k_scan(unsigned int* hist, SelState* st) {
  if (threadIdx.x == 0) {
    int need = st->kneed;
    unsigned int cum = 0;
    for (int b = 255; b >= 0; --b) {
      unsigned int h = hist[b];
      if (cum + h >= (unsigned int)need) {
        st->P = (st->P << 8) | (unsigned int)b;
        st->kneed = need - (int)cum;
        break;
      }
      cum += h;
    }
  }
  __syncthreads();
  hist[threadIdx.x] = 0;  // ready for next round
}

__global__ void k_compact(const unsigned int* __restrict__ keys, SelState* st,
                          int* __restrict__ idx, int* __restrict__ eq) {
  int p = blockIdx.x * 256 + threadIdx.x;
  unsigned int key = keys[p];
  unsigned int P = st->P;
  if (key > P) {
    int pos = atomicAdd(&st->nGreater, 1);
    idx[pos] = p;
  } else if (key == P) {
    int e = atomicAdd(&st->nEqual, 1);
    if (e < 4096) eq[e] = p;
  }
}

__global__ void k_finalize(SelState* st, int* idx, int* eq) {
  if (threadIdx.x != 0) return;
  int n = st->nEqual;
  if (n > 4096) n = 4096;
  for (int i = 1; i < n; ++i) {  // insertion sort ascending (n tiny, usually 1)
    int v = eq[i], j = i - 1;
    while (j >= 0 && eq[j] > v) { eq[j + 1] = eq[j]; --j; }
    eq[j + 1] = v;
  }
  int g = st->nGreater;
  for (int i = 0; i < st->kneed; ++i) idx[g + i] = eq[i];
}

__global__ void k_transpose(const float* __restrict__ in, float* __restrict__ out, int rows) {
  int o = blockIdx.x, c = threadIdx.x;
  out[(size_t)c * rows + o] = in[(size_t)o * 256 + c];
}

// gather rows at idx and project to Q,K,V (2048 x 256 each)
__global__ void k_qkv(const float* __restrict__ down, const float* __restrict__ s,
                      const int* __restrict__ idx, const float* __restrict__ wT,
                      const float* __restrict__ bias, float* __restrict__ Q,
                      float* __restrict__ K, float* __restrict__ V) {
  __shared__ float xq[256], xk[256];
  int j = blockIdx.x, c = threadIdx.x;
  int p = idx[j];
  xq[c] = down[(size_t)c * HWP + p];
  xk[c] = s[(size_t)c * HWP + p];
  __syncthreads();
  float aq = bias[c], ak = bias[256 + c], av = bias[512 + c];
  for (int i = 0; i < 256; ++i) {
    float xv = xq[i], kv = xk[i];
    aq += xv * wT[i * 768 + c];
    ak += kv * wT[i * 768 + 256 + c];
    av += kv * wT[i * 768 + 512 + c];
  }
  Q[j * 256 + c] = aq;
  K[j * 256 + c] = ak;
  V[j * 256 + c] = av;
}

// one block per (query row, head): full-softmax attention over 2048 keys
__global__ __launch_bounds__(256) void k_attn(const float* __restrict__ Q,
                                              const float* __restrict__ K,
                                              const float* __restrict__ V,
                                              float* __restrict__ O) {
  int jq = blockIdx.x, h = blockIdx.y, t = threadIdx.x;
  int hd0 = h * 32;
  __shared__ float qv[32];
  __shared__ float red[256];
  __shared__ float mat[256 * 33];
  if (t < 32) qv[t] = Q[jq * 256 + hd0 + t];
  __syncthreads();
  const float scale = 0.17677669529663687f;  // 1/sqrt(32)
  float sc[8];
#pragma unroll
  for (int r = 0; r < 8; ++r) {
    const float* kp = K + (size_t)(r * 256 + t) * 256 + hd0;
    float a = 0.f;
#pragma unroll
    for (int d = 0; d < 32; ++d) a += qv[d] * kp[d];
    sc[r] = a * scale;
  }
  float m = sc[0];
#pragma unroll
  for (int r = 1; r < 8; ++r) m = fmaxf(m, sc[r]);
  float s = 0.f;
  float acc[32];
#pragma unroll
  for (int d = 0; d < 32; ++d) acc[d] = 0.f;
#pragma unroll
  for (int r = 0; r < 8; ++r) {
    float wv = __expf(sc[r] - m);
    s += wv;
    const float* vp = V + (size_t)(r * 256 + t) * 256 + hd0;
#pragma unroll
    for (int d = 0; d < 32; ++d) acc[d] += wv * vp[d];
  }
  red[t] = m;
  __syncthreads();
  for (int off = 128; off > 0; off >>= 1) {
    if (t < off) red[t] = fmaxf(red[t], red[t + off]);
    __syncthreads();
  }
  float M = red[0];
  __syncthreads();
  float wsc = __expf(m - M);
  red[t] = s * wsc;
  __syncthreads();
  for (int off = 128; off > 0; off >>= 1) {
    if (t < off) red[t] += red[t + off];
    __syncthreads();
  }
  float S = red[0];
#pragma unroll
  for (int d = 0; d < 32; ++d) mat[t * 33 + d] = acc[d] * wsc;
  __syncthreads();
  if (t < 32) {
    float o = 0.f;
    for (int i = 0; i < 256; ++i) o += mat[i * 33 + t];
    O[jq * 256 + hd0 + t] = o / S;
  }
}

__global__ void k_copy(const float4* __restrict__ in, float4* __restrict__ out, int n4) {
  int i = blockIdx.x * blockDim.x + threadIdx.x;
  int stride = gridDim.x * blockDim.x;
  for (; i < n4; i += stride) out[i] = in[i];
}

// out-projection fused with scatter into final output columns
__global__ void k_outproj(const float* __restrict__ Oa, const float* __restrict__ owT,
                          const float* __restrict__ ob, const int* __restrict__ idx,
                          float* __restrict__ out) {
  __shared__ float xo[256];
  int j = blockIdx.x, c = threadIdx.x;
  xo[c] = Oa[j * 256 + c];
  __syncthreads();
  float a = ob[c];
  for (int i = 0; i < 256; ++i) a += xo[i] * owT[i * 256 + c];
  out[(size_t)c * HWP + idx[j]] = a;
}

extern "C" void kernel_launch(void* const* d_in, const int* in_sizes, int n_in,
                              void* d_out, int out_size, void* d_ws, size_t ws_size,
                              hipStream_t stream) {
  const float* down  = (const float*)d_in[0];
  const float* swint = (const float*)d_in[1];
  const float* wt_w  = (const float*)d_in[2];
  const float* wt_b  = (const float*)d_in[3];
  const float* up_dw = (const float*)d_in[4];
  const float* up_db = (const float*)d_in[5];
  const float* up_cw = (const float*)d_in[6];
  const float* up_cb = (const float*)d_in[7];
  const float* gate_w = (const float*)d_in[8];
  const float* in_w  = (const float*)d_in[10];
  const float* in_b  = (const float*)d_in[11];
  const float* out_w = (const float*)d_in[12];
  const float* out_b = (const float*)d_in[13];
  float* out = (float*)d_out;
  char* ws = (char*)d_ws;

  float* bufA = (float*)ws;
  float* bufB = (float*)(ws + BUF_B_OFF);
  unsigned int* keys = (unsigned int*)(ws + KEYS_OFF);
  unsigned int* hist = (unsigned int*)(ws + HIST_OFF);
  SelState* st = (SelState*)(ws + STATE_OFF);
  int* idx = (int*)(ws + IDX_OFF);
  int* eq = (int*)(ws + EQ_OFF);
  float* Q = (float*)(ws + Q_OFF);
  float* Km = (float*)(ws + K_OFF);
  float* V = (float*)(ws + V_OFF);
  float* Oa = (float*)(ws + OA_OFF);
  float* wTi = (float*)(ws + WTI_OFF);
  float* wTo = (float*)(ws + WTO_OFF);

  k_init<<<1, 256, 0, stream>>>(hist, st);

  // gate + exact top-k (radix select over orderable keys)
  k_gate<<<256, 256, 0, stream>>>(down, gate_w, keys);
  for (int r = 0; r < 4; ++r) {
    k_hist<<<256, 256, 0, stream>>>(keys, hist, st, r);
    k_scan<<<1, 256, 0, stream>>>(hist, st);
  }
  k_compact<<<256, 256, 0, stream>>>(keys, st, idx, eq);
  k_finalize<<<1, 64, 0, stream>>>(st, idx, eq);

  // passthrough copy of down into output (scatter later overwrites idx columns)
  k_copy<<<4096, 256, 0, stream>>>((const float4*)down, (float4*)out, 4194304);

  // upsampler chain
  k_wtconv<<<256, 64, 0, stream>>>(swint, wt_w, wt_b, bufA);
  k_deconv<8><<<dim3(1, 256), 256, 0, stream>>>(bufA, up_dw, up_db, bufB);
  k_conv3<16><<<dim3(1, 256), 256, 0, stream>>>(bufB, up_cw, up_cb, bufA);
  k_deconv<16><<<dim3(4, 256), 256, 0, stream>>>(bufA, up_dw + 1048576, up_db + 256, bufB);
  k_conv3<32><<<dim3(4, 256), 256, 0, stream>>>(bufB, up_cw + 589824, up_cb + 256, bufA);
  k_deconv<32><<<dim3(16, 256), 256, 0, stream>>>(bufA, up_dw + 2097152, up_db + 512, bufB);
  k_conv3<64><<<dim3(16, 256), 256, 0, stream>>>(bufB, up_cw + 1179648, up_cb + 512, bufA);
  k_deconv<64><<<dim3(64, 256), 256, 0, stream>>>(bufA, up_dw + 3145728, up_db + 768, bufB);
  k_conv3<128><<<dim3(64, 256), 256, 0, stream>>>(bufB, up_cw + 1769472, up_cb + 768, bufA);
  k_deconv<128><<<dim3(256, 256), 256, 0, stream>>>(bufA, up_dw + 4194304, up_db + 1024, bufB);
  k_conv3<256><<<dim3(256, 256), 256, 0, stream>>>(bufB, up_cw + 2359296, up_cb + 1024, bufA);

  // attention path (bufB region is dead now; QKV/O/wT live there)
  k_transpose<<<768, 256, 0, stream>>>(in_w, wTi, 768);
  k_transpose<<<256, 256, 0, stream>>>(out_w, wTo, 256);
  k_qkv<<<2048, 256, 0, stream>>>(down, bufA, idx, wTi, in_b, Q, Km, V);
  k_attn<<<dim3(2048, 8), 256, 0, stream>>>(Q, Km, V, Oa);
  k_outproj<<<2048, 256, 0, stream>>>(Oa, wTo, out_b, idx, out);
}